// Round 2
// baseline (2033.746 us; speedup 1.0000x reference)
//
#include <hip/hip_runtime.h>

#define HF 64  // hidden feature width (both convs output 64)

// ---------------- degree / normalization ----------------
__global__ void count_deg_kernel(const int* __restrict__ dst, float* __restrict__ deg, int E) {
    int e = blockIdx.x * blockDim.x + threadIdx.x;
    if (e < E) atomicAdd(&deg[dst[e]], 1.0f);
}

__global__ void finalize_dinv_kernel(float* deg, int N) {
    int i = blockIdx.x * blockDim.x + threadIdx.x;
    if (i < N) deg[i] = rsqrtf(deg[i] + 1.0f);
}

// ---------------- node GEMM: Y[n][f] = (sum_k X[n][k] W[k][f]) * scale[n] ----------------
template <int K>
__global__ __launch_bounds__(256) void gemm_scale_kernel(const float* __restrict__ X,
                                                         const float* __restrict__ W,
                                                         const float* __restrict__ scale,
                                                         float* __restrict__ Y, int N) {
    __shared__ float Wl[K * HF];
    __shared__ float xs[32 * K];
    for (int i = threadIdx.x; i < K * HF; i += 256) Wl[i] = W[i];

    int node0 = blockIdx.x * 32;
    const float4* X4 = (const float4*)(X + (size_t)node0 * K);
    float4* xs4 = (float4*)xs;
    int totalf4 = 32 * K / 4;
    for (int i = threadIdx.x; i < totalf4; i += 256) {
        int n = i / (K / 4);
        if (node0 + n < N) xs4[i] = X4[i];
    }
    __syncthreads();

    int wave = threadIdx.x >> 6, f = threadIdx.x & 63;
    for (int n = wave; n < 32; n += 4) {
        int node = node0 + n;
        if (node >= N) break;
        const float4* xr = (const float4*)&xs[n * K];
        float acc = 0.0f;
#pragma unroll
        for (int k4 = 0; k4 < K / 4; ++k4) {
            float4 xv = xr[k4];
            acc += xv.x * Wl[(k4 * 4 + 0) * HF + f];
            acc += xv.y * Wl[(k4 * 4 + 1) * HF + f];
            acc += xv.z * Wl[(k4 * 4 + 2) * HF + f];
            acc += xv.w * Wl[(k4 * 4 + 3) * HF + f];
        }
        Y[(size_t)node * HF + f] = acc * scale[node];
    }
}

// ---------------- edge scatter: agg[dst] += hs[src]  (hs pre-scaled by dinv[src]) --------
__global__ __launch_bounds__(256) void scatter_kernel(const float* __restrict__ hs,
                                                      const int* __restrict__ src,
                                                      const int* __restrict__ dst,
                                                      float* __restrict__ agg, int E) {
    int e = blockIdx.x * 4 + (threadIdx.x >> 6);
    if (e >= E) return;
    int f = threadIdx.x & 63;
    int s = src[e];
    int d = dst[e];
    float v = hs[(size_t)s * HF + f];
    atomicAdd(&agg[(size_t)d * HF + f], v);
}

// ---------------- epilogue: h = relu(dinv[i]*(agg+hs) + b) (in-place into hs) -----------
__global__ void epi_kernel(const float* __restrict__ agg, float* __restrict__ hs,
                           const float* __restrict__ dinv, const float* __restrict__ b,
                           long total) {
    long i = (long)blockIdx.x * blockDim.x + threadIdx.x;
    if (i >= total) return;
    int node = (int)(i >> 6);
    int f = (int)(i & 6 * 10 + 3);  // placeholder avoided below
    f = (int)(i & 63);
    float v = dinv[node] * (agg[i] + hs[i]) + b[f];
    hs[i] = fmaxf(v, 0.0f);
}

// ---------------- fused epilogue2 + mean-pool accumulation ------------------------------
__global__ __launch_bounds__(256) void epi_pool_kernel(const float* __restrict__ agg,
                                                       const float* __restrict__ hs,
                                                       const float* __restrict__ dinv,
                                                       const float* __restrict__ b,
                                                       const int* __restrict__ batch,
                                                       float* __restrict__ pool,
                                                       float* __restrict__ cnt, int N) {
    int node = blockIdx.x * 4 + (threadIdx.x >> 6);
    if (node >= N) return;
    int f = threadIdx.x & 63;
    size_t i = (size_t)node * HF + f;
    float v = fmaxf(dinv[node] * (agg[i] + hs[i]) + b[f], 0.0f);
    int g = batch[node];
    atomicAdd(&pool[g * HF + f], v);
    if (f == 0) atomicAdd(&cnt[g], 1.0f);
}

// ---------------- final: out[g][c] = (pool[g]/cnt[g]) @ Wlin + blin ---------------------
__global__ void final_kernel(const float* __restrict__ pool, const float* __restrict__ cnt,
                             const float* __restrict__ Wlin, const float* __restrict__ blin,
                             float* __restrict__ out) {
    int g = blockIdx.x;
    int f = threadIdx.x;  // 64
    float v = pool[g * HF + f] / fmaxf(cnt[g], 1.0f);
    float s0 = v * Wlin[f * 2 + 0];
    float s1 = v * Wlin[f * 2 + 1];
#pragma unroll
    for (int off = 32; off > 0; off >>= 1) {
        s0 += __shfl_down(s0, off);
        s1 += __shfl_down(s1, off);
    }
    if (f == 0) {
        out[g * 2 + 0] = s0 + blin[0];
        out[g * 2 + 1] = s1 + blin[1];
    }
}

extern "C" void kernel_launch(void* const* d_in, const int* in_sizes, int n_in,
                              void* d_out, int out_size, void* d_ws, size_t ws_size,
                              hipStream_t stream) {
    const float* x    = (const float*)d_in[0];
    const int*   ei   = (const int*)d_in[1];
    const int*   bat  = (const int*)d_in[2];
    const float* W1   = (const float*)d_in[3];
    const float* b1   = (const float*)d_in[4];
    const float* W2   = (const float*)d_in[5];
    const float* b2   = (const float*)d_in[6];
    const float* Wlin = (const float*)d_in[7];
    const float* blin = (const float*)d_in[8];

    const int N = in_sizes[2];            // 100000 (batch has one entry per node)
    const int E = in_sizes[1] / 2;        // 3200000
    const int G = out_size / 2;           // 512
    const int* src = ei;
    const int* dstv = ei + E;

    float* ws = (float*)d_ws;
    size_t off = ((size_t)N + 63) & ~(size_t)63;
    float* dinv = ws;                         // N
    float* bufA = ws + off;                   // N*64
    float* bufB = bufA + (size_t)N * HF;      // N*64
    float* pool = bufB + (size_t)N * HF;      // G*64
    float* cnt  = pool + (size_t)G * HF;      // G

    // normalization
    hipMemsetAsync(dinv, 0, (size_t)N * sizeof(float), stream);
    count_deg_kernel<<<(E + 255) / 256, 256, 0, stream>>>(dstv, dinv, E);
    finalize_dinv_kernel<<<(N + 255) / 256, 256, 0, stream>>>(dinv, N);

    // ---- conv1: bufA = (x@W1)*dinv ; bufB = scatter ; h1 -> bufA ----
    gemm_scale_kernel<128><<<(N + 31) / 32, 256, 0, stream>>>(x, W1, dinv, bufA, N);
    hipMemsetAsync(bufB, 0, (size_t)N * HF * sizeof(float), stream);
    scatter_kernel<<<(E + 3) / 4, 256, 0, stream>>>(bufA, src, dstv, bufB, E);
    long total = (long)N * HF;
    epi_kernel<<<(int)((total + 255) / 256), 256, 0, stream>>>(bufB, bufA, dinv, b1, total);

    // ---- conv2: bufB = (h1@W2)*dinv ; bufA = scatter ; fused relu+pool ----
    gemm_scale_kernel<64><<<(N + 31) / 32, 256, 0, stream>>>(bufA, W2, dinv, bufB, N);
    hipMemsetAsync(bufA, 0, (size_t)N * HF * sizeof(float), stream);
    scatter_kernel<<<(E + 3) / 4, 256, 0, stream>>>(bufB, src, dstv, bufA, E);

    hipMemsetAsync(pool, 0, ((size_t)G * HF + G) * sizeof(float), stream);
    epi_pool_kernel<<<(N + 3) / 4, 256, 0, stream>>>(bufA, bufB, dinv, b2, bat, pool, cnt, N);

    final_kernel<<<G, HF, 0, stream>>>(pool, cnt, Wlin, blin, (float*)d_out);
}

// Round 5
// 1304.800 us; speedup vs baseline: 1.5587x; 1.5587x over previous
//
#include <hip/hip_runtime.h>

#define HF 64  // hidden feature width (both convs output 64)

// ---------------- CSR build: histogram ----------------
__global__ void hist_kernel(const int* __restrict__ dst, int* __restrict__ deg, int E) {
    int e = blockIdx.x * blockDim.x + threadIdx.x;
    if (e < E) atomicAdd(&deg[dst[e]], 1);
}

// 1024 elements per block (256 thr x 4), block sums out
__global__ __launch_bounds__(256) void scan_partial(const int* __restrict__ deg,
                                                    int* __restrict__ blocksum, int N) {
    __shared__ int red[256];
    int base = blockIdx.x * 1024 + threadIdx.x * 4;
    int s = 0;
#pragma unroll
    for (int j = 0; j < 4; ++j) {
        int i = base + j;
        if (i < N) s += deg[i];
    }
    red[threadIdx.x] = s;
    __syncthreads();
    for (int o = 128; o > 0; o >>= 1) {
        if (threadIdx.x < o) red[threadIdx.x] += red[threadIdx.x + o];
        __syncthreads();
    }
    if (threadIdx.x == 0) blocksum[blockIdx.x] = red[0];
}

// single block exclusive scan of <=256 block sums
__global__ __launch_bounds__(256) void scan_blocksums(int* __restrict__ blocksum, int nb) {
    __shared__ int lds[256];
    int t = threadIdx.x;
    int v = (t < nb) ? blocksum[t] : 0;
    lds[t] = v;
    __syncthreads();
    for (int o = 1; o < 256; o <<= 1) {
        int add = (t >= o) ? lds[t - o] : 0;
        __syncthreads();
        lds[t] += add;
        __syncthreads();
    }
    if (t < nb) blocksum[t] = lds[t] - v;  // exclusive
}

// apply: cursor[i] = global exclusive prefix (start offset); dinv[i] = rsqrt(deg+1)
__global__ __launch_bounds__(256) void scan_apply(const int* __restrict__ deg,
                                                  const int* __restrict__ blocksum,
                                                  int* __restrict__ cursor,
                                                  float* __restrict__ dinv, int N) {
    __shared__ int lds[256];
    int base = blockIdx.x * 1024 + threadIdx.x * 4;
    int v[4];
    int s = 0;
#pragma unroll
    for (int j = 0; j < 4; ++j) {
        int i = base + j;
        v[j] = (i < N) ? deg[i] : 0;
        s += v[j];
    }
    lds[threadIdx.x] = s;
    __syncthreads();
    for (int o = 1; o < 256; o <<= 1) {
        int add = (threadIdx.x >= o) ? lds[threadIdx.x - o] : 0;
        __syncthreads();
        lds[threadIdx.x] += add;
        __syncthreads();
    }
    int run = blocksum[blockIdx.x] + lds[threadIdx.x] - s;  // exclusive thread offset
#pragma unroll
    for (int j = 0; j < 4; ++j) {
        int i = base + j;
        if (i < N) {
            cursor[i] = run;
            dinv[i] = rsqrtf((float)v[j] + 1.0f);
            run += v[j];
        }
    }
}

// fill: csr_src[pos] = src[e], pos via atomic cursor; after this cursor[d] == end offset
__global__ void fill_kernel(const int* __restrict__ src, const int* __restrict__ dst,
                            int* __restrict__ cursor, int* __restrict__ csr_src, int E) {
    int e = blockIdx.x * blockDim.x + threadIdx.x;
    if (e < E) {
        int d = dst[e];
        int pos = atomicAdd(&cursor[d], 1);
        csr_src[pos] = src[e];
    }
}

// ---------------- node GEMM: Y[n][f] = (sum_k X[n][k] W[k][f]) * scale[n] ----------------
template <int K>
__global__ __launch_bounds__(256) void gemm_scale_kernel(const float* __restrict__ X,
                                                         const float* __restrict__ W,
                                                         const float* __restrict__ scale,
                                                         float* __restrict__ Y, int N) {
    __shared__ float Wl[K * HF];
    __shared__ float xs[32 * K];
    for (int i = threadIdx.x; i < K * HF; i += 256) Wl[i] = W[i];

    int node0 = blockIdx.x * 32;
    const float4* X4 = (const float4*)(X + (size_t)node0 * K);
    float4* xs4 = (float4*)xs;
    int totalf4 = 32 * K / 4;
    for (int i = threadIdx.x; i < totalf4; i += 256) {
        int n = i / (K / 4);
        if (node0 + n < N) xs4[i] = X4[i];
    }
    __syncthreads();

    int wave = threadIdx.x >> 6, f = threadIdx.x & 63;
    for (int n = wave; n < 32; n += 4) {
        int node = node0 + n;
        if (node >= N) break;
        const float4* xr = (const float4*)&xs[n * K];
        float acc = 0.0f;
#pragma unroll
        for (int k4 = 0; k4 < K / 4; ++k4) {
            float4 xv = xr[k4];
            acc += xv.x * Wl[(k4 * 4 + 0) * HF + f];
            acc += xv.y * Wl[(k4 * 4 + 1) * HF + f];
            acc += xv.z * Wl[(k4 * 4 + 2) * HF + f];
            acc += xv.w * Wl[(k4 * 4 + 3) * HF + f];
        }
        Y[(size_t)node * HF + f] = acc * scale[node];
    }
}

// ---------------- conv1 aggregation + epilogue: out = relu(dinv*(gather-sum + self) + b) --
__global__ __launch_bounds__(256) void agg_relu_kernel(const float* __restrict__ hs,
                                                       const int* __restrict__ cursor,
                                                       const int* __restrict__ deg,
                                                       const int* __restrict__ csr_src,
                                                       const float* __restrict__ dinv,
                                                       const float* __restrict__ b,
                                                       float* __restrict__ out, int N) {
    int d = blockIdx.x * 4 + (threadIdx.x >> 6);
    if (d >= N) return;
    int f = threadIdx.x & 63;
    int end = cursor[d];
    int beg = end - deg[d];
    float acc = 0.0f;
    for (int e = beg; e < end; ++e) {
        int s = csr_src[e];
        acc += hs[(size_t)s * HF + f];
    }
    float v = dinv[d] * (acc + hs[(size_t)d * HF + f]) + b[f];
    out[(size_t)d * HF + f] = fmaxf(v, 0.0f);
}

// ---------------- conv2 aggregation + epilogue + mean-pool accumulation ------------------
__global__ __launch_bounds__(256) void agg_pool_kernel(const float* __restrict__ hs,
                                                       const int* __restrict__ cursor,
                                                       const int* __restrict__ deg,
                                                       const int* __restrict__ csr_src,
                                                       const float* __restrict__ dinv,
                                                       const float* __restrict__ b,
                                                       const int* __restrict__ batch,
                                                       float* __restrict__ pool,
                                                       float* __restrict__ cnt, int N) {
    int d = blockIdx.x * 4 + (threadIdx.x >> 6);
    if (d >= N) return;
    int f = threadIdx.x & 63;
    int end = cursor[d];
    int beg = end - deg[d];
    float acc = 0.0f;
    for (int e = beg; e < end; ++e) {
        int s = csr_src[e];
        acc += hs[(size_t)s * HF + f];
    }
    float v = fmaxf(dinv[d] * (acc + hs[(size_t)d * HF + f]) + b[f], 0.0f);
    int g = batch[d];
    atomicAdd(&pool[g * HF + f], v);
    if (f == 0) atomicAdd(&cnt[g], 1.0f);
}

// ---------------- final: out[g][c] = (pool[g]/cnt[g]) @ Wlin + blin ---------------------
__global__ void final_kernel(const float* __restrict__ pool, const float* __restrict__ cnt,
                             const float* __restrict__ Wlin, const float* __restrict__ blin,
                             float* __restrict__ out) {
    int g = blockIdx.x;
    int f = threadIdx.x;  // 64
    float v = pool[g * HF + f] / fmaxf(cnt[g], 1.0f);
    float s0 = v * Wlin[f * 2 + 0];
    float s1 = v * Wlin[f * 2 + 1];
#pragma unroll
    for (int off = 32; off > 0; off >>= 1) {
        s0 += __shfl_down(s0, off);
        s1 += __shfl_down(s1, off);
    }
    if (f == 0) {
        out[g * 2 + 0] = s0 + blin[0];
        out[g * 2 + 1] = s1 + blin[1];
    }
}

extern "C" void kernel_launch(void* const* d_in, const int* in_sizes, int n_in,
                              void* d_out, int out_size, void* d_ws, size_t ws_size,
                              hipStream_t stream) {
    const float* x    = (const float*)d_in[0];
    const int*   ei   = (const int*)d_in[1];
    const int*   bat  = (const int*)d_in[2];
    const float* W1   = (const float*)d_in[3];
    const float* b1   = (const float*)d_in[4];
    const float* W2   = (const float*)d_in[5];
    const float* b2   = (const float*)d_in[6];
    const float* Wlin = (const float*)d_in[7];
    const float* blin = (const float*)d_in[8];

    const int N = in_sizes[2];      // 100000
    const int E = in_sizes[1] / 2;  // 3200000
    const int G = out_size / 2;     // 512
    const int* src  = ei;
    const int* dstv = ei + E;

    // ---- workspace layout (all offsets 16B-aligned for N,E multiples of 4) ----
    int*   deg      = (int*)d_ws;             // N
    int*   cursor   = deg + N;                // N
    int*   blocksum = cursor + N;             // 256
    int*   csr_src  = blocksum + 256;         // E
    float* dinv     = (float*)(csr_src + E);  // N
    float* bufA     = dinv + N;               // N*64
    float* bufB     = bufA + (size_t)N * HF;  // N*64
    float* pool     = bufB + (size_t)N * HF;  // G*64
    float* cnt      = pool + (size_t)G * HF;  // G

    int nb = (N + 1023) / 1024;  // 98 <= 256

    // ---- CSR build (once, reused by both convs) ----
    hipMemsetAsync(deg, 0, (size_t)N * sizeof(int), stream);
    hist_kernel<<<(E + 255) / 256, 256, 0, stream>>>(dstv, deg, E);
    scan_partial<<<nb, 256, 0, stream>>>(deg, blocksum, N);
    scan_blocksums<<<1, 256, 0, stream>>>(blocksum, nb);
    scan_apply<<<nb, 256, 0, stream>>>(deg, blocksum, cursor, dinv, N);
    fill_kernel<<<(E + 255) / 256, 256, 0, stream>>>(src, dstv, cursor, csr_src, E);
    // now: cursor[d] = end offset, cursor[d]-deg[d] = begin offset

    // ---- conv1: bufA = (x@W1)*dinv ; bufB = relu(aggregate) ----
    gemm_scale_kernel<128><<<(N + 31) / 32, 256, 0, stream>>>(x, W1, dinv, bufA, N);
    agg_relu_kernel<<<(N + 3) / 4, 256, 0, stream>>>(bufA, cursor, deg, csr_src, dinv, b1,
                                                     bufB, N);

    // ---- conv2: bufA = (h1@W2)*dinv ; aggregate + relu + pool (h2 never materialized) ----
    gemm_scale_kernel<64><<<(N + 31) / 32, 256, 0, stream>>>(bufB, W2, dinv, bufA, N);
    hipMemsetAsync(pool, 0, ((size_t)G * HF + G) * sizeof(float), stream);
    agg_pool_kernel<<<(N + 3) / 4, 256, 0, stream>>>(bufA, cursor, deg, csr_src, dinv, b2,
                                                     bat, pool, cnt, N);

    final_kernel<<<G, HF, 0, stream>>>(pool, cnt, Wlin, blin, (float*)d_out);
}

// Round 12
// 983.110 us; speedup vs baseline: 2.0687x; 1.3272x over previous
//
#include <hip/hip_runtime.h>

#define HF 64  // hidden feature width (both convs output 64)

// ---------------- CSR build: histogram ----------------
__global__ void hist_kernel(const int* __restrict__ dst, int* __restrict__ deg, int E) {
    int e = blockIdx.x * blockDim.x + threadIdx.x;
    if (e < E) atomicAdd(&deg[dst[e]], 1);
}

// 1024 elements per block (256 thr x 4), block sums out
__global__ __launch_bounds__(256) void scan_partial(const int* __restrict__ deg,
                                                    int* __restrict__ blocksum, int N) {
    __shared__ int red[256];
    int base = blockIdx.x * 1024 + threadIdx.x * 4;
    int s = 0;
#pragma unroll
    for (int j = 0; j < 4; ++j) {
        int i = base + j;
        if (i < N) s += deg[i];
    }
    red[threadIdx.x] = s;
    __syncthreads();
    for (int o = 128; o > 0; o >>= 1) {
        if (threadIdx.x < o) red[threadIdx.x] += red[threadIdx.x + o];
        __syncthreads();
    }
    if (threadIdx.x == 0) blocksum[blockIdx.x] = red[0];
}

// single block exclusive scan of <=256 block sums
__global__ __launch_bounds__(256) void scan_blocksums(int* __restrict__ blocksum, int nb) {
    __shared__ int lds[256];
    int t = threadIdx.x;
    int v = (t < nb) ? blocksum[t] : 0;
    lds[t] = v;
    __syncthreads();
    for (int o = 1; o < 256; o <<= 1) {
        int add = (t >= o) ? lds[t - o] : 0;
        __syncthreads();
        lds[t] += add;
        __syncthreads();
    }
    if (t < nb) blocksum[t] = lds[t] - v;  // exclusive
}

// apply: cursor[i] = global exclusive prefix (start offset); dinv[i] = rsqrt(deg+1)
__global__ __launch_bounds__(256) void scan_apply(const int* __restrict__ deg,
                                                  const int* __restrict__ blocksum,
                                                  int* __restrict__ cursor,
                                                  float* __restrict__ dinv, int N) {
    __shared__ int lds[256];
    int base = blockIdx.x * 1024 + threadIdx.x * 4;
    int v[4];
    int s = 0;
#pragma unroll
    for (int j = 0; j < 4; ++j) {
        int i = base + j;
        v[j] = (i < N) ? deg[i] : 0;
        s += v[j];
    }
    lds[threadIdx.x] = s;
    __syncthreads();
    for (int o = 1; o < 256; o <<= 1) {
        int add = (threadIdx.x >= o) ? lds[threadIdx.x - o] : 0;
        __syncthreads();
        lds[threadIdx.x] += add;
        __syncthreads();
    }
    int run = blocksum[blockIdx.x] + lds[threadIdx.x] - s;  // exclusive thread offset
#pragma unroll
    for (int j = 0; j < 4; ++j) {
        int i = base + j;
        if (i < N) {
            cursor[i] = run;
            dinv[i] = rsqrtf((float)v[j] + 1.0f);
            run += v[j];
        }
    }
}

// fill: csr_src[pos] = src[e], pos via atomic cursor; after this cursor[d] == end offset
__global__ void fill_kernel(const int* __restrict__ src, const int* __restrict__ dst,
                            int* __restrict__ cursor, int* __restrict__ csr_src, int E) {
    int e = blockIdx.x * blockDim.x + threadIdx.x;
    if (e < E) {
        int d = dst[e];
        int pos = atomicAdd(&cursor[d], 1);
        csr_src[pos] = src[e];
    }
}

// ---------------- node GEMM: Y[n][f] = (sum_k X[n][k] W[k][f]) * scale[n] ----------------
template <int K>
__global__ __launch_bounds__(256) void gemm_scale_kernel(const float* __restrict__ X,
                                                         const float* __restrict__ W,
                                                         const float* __restrict__ scale,
                                                         float* __restrict__ Y, int N) {
    __shared__ float Wl[K * HF];
    __shared__ float xs[32 * K];
    for (int i = threadIdx.x; i < K * HF; i += 256) Wl[i] = W[i];

    int node0 = blockIdx.x * 32;
    const float4* X4 = (const float4*)(X + (size_t)node0 * K);
    float4* xs4 = (float4*)xs;
    int totalf4 = 32 * K / 4;
    for (int i = threadIdx.x; i < totalf4; i += 256) {
        int n = i / (K / 4);
        if (node0 + n < N) xs4[i] = X4[i];
    }
    __syncthreads();

    int wave = threadIdx.x >> 6, f = threadIdx.x & 63;
    for (int n = wave; n < 32; n += 4) {
        int node = node0 + n;
        if (node >= N) break;
        const float4* xr = (const float4*)&xs[n * K];
        float acc = 0.0f;
#pragma unroll
        for (int k4 = 0; k4 < K / 4; ++k4) {
            float4 xv = xr[k4];
            acc += xv.x * Wl[(k4 * 4 + 0) * HF + f];
            acc += xv.y * Wl[(k4 * 4 + 1) * HF + f];
            acc += xv.z * Wl[(k4 * 4 + 2) * HF + f];
            acc += xv.w * Wl[(k4 * 4 + 3) * HF + f];
        }
        Y[(size_t)node * HF + f] = acc * scale[node];
    }
}

// ---- wave-cooperative gather-sum over one dst node's edge list ----
// Lane f: 32 edge indices staged per chunk (lanes 0-31 via coalesced load, dup in 32-63),
// broadcast with readlane -> 32 INDEPENDENT gathers in flight (vs serial chain).
__device__ __forceinline__ float edge_gather_sum(const float* __restrict__ hs,
                                                 const int* __restrict__ csr_src,
                                                 int beg, int end, int f) {
    float acc = 0.0f;
    for (int base = beg; base < end; base += 32) {
        int li = base + (f & 31);
        int myidx = csr_src[li < end ? li : beg];  // clamp: safe row, result masked
        int rem = end - base;                      // uniform
#pragma unroll
        for (int j = 0; j < 32; ++j) {
            int s = __builtin_amdgcn_readlane(myidx, j);
            float v = hs[(size_t)s * HF + f];
            acc += (j < rem) ? v : 0.0f;
        }
    }
    return acc;
}

// ---------------- conv1 aggregation + epilogue: out = relu(dinv*(gather-sum + self) + b) --
__global__ __launch_bounds__(256) void agg_relu_kernel(const float* __restrict__ hs,
                                                       const int* __restrict__ cursor,
                                                       const int* __restrict__ deg,
                                                       const int* __restrict__ csr_src,
                                                       const float* __restrict__ dinv,
                                                       const float* __restrict__ b,
                                                       float* __restrict__ out, int N) {
    int d = blockIdx.x * 4 + (threadIdx.x >> 6);
    if (d >= N) return;
    int f = threadIdx.x & 63;
    int end = cursor[d];
    int beg = end - deg[d];
    float acc = edge_gather_sum(hs, csr_src, beg, end, f);
    float v = dinv[d] * (acc + hs[(size_t)d * HF + f]) + b[f];
    out[(size_t)d * HF + f] = fmaxf(v, 0.0f);
}

// ---------------- conv2 aggregation + epilogue + mean-pool accumulation ------------------
__global__ __launch_bounds__(256) void agg_pool_kernel(const float* __restrict__ hs,
                                                       const int* __restrict__ cursor,
                                                       const int* __restrict__ deg,
                                                       const int* __restrict__ csr_src,
                                                       const float* __restrict__ dinv,
                                                       const float* __restrict__ b,
                                                       const int* __restrict__ batch,
                                                       float* __restrict__ pool,
                                                       float* __restrict__ cnt, int N) {
    int d = blockIdx.x * 4 + (threadIdx.x >> 6);
    if (d >= N) return;
    int f = threadIdx.x & 63;
    int end = cursor[d];
    int beg = end - deg[d];
    float acc = edge_gather_sum(hs, csr_src, beg, end, f);
    float v = fmaxf(dinv[d] * (acc + hs[(size_t)d * HF + f]) + b[f], 0.0f);
    int g = batch[d];
    atomicAdd(&pool[g * HF + f], v);
    if (f == 0) atomicAdd(&cnt[g], 1.0f);
}

// ---------------- final: out[g][c] = (pool[g]/cnt[g]) @ Wlin + blin ---------------------
__global__ void final_kernel(const float* __restrict__ pool, const float* __restrict__ cnt,
                             const float* __restrict__ Wlin, const float* __restrict__ blin,
                             float* __restrict__ out) {
    int g = blockIdx.x;
    int f = threadIdx.x;  // 64
    float v = pool[g * HF + f] / fmaxf(cnt[g], 1.0f);
    float s0 = v * Wlin[f * 2 + 0];
    float s1 = v * Wlin[f * 2 + 1];
#pragma unroll
    for (int off = 32; off > 0; off >>= 1) {
        s0 += __shfl_down(s0, off);
        s1 += __shfl_down(s1, off);
    }
    if (f == 0) {
        out[g * 2 + 0] = s0 + blin[0];
        out[g * 2 + 1] = s1 + blin[1];
    }
}

extern "C" void kernel_launch(void* const* d_in, const int* in_sizes, int n_in,
                              void* d_out, int out_size, void* d_ws, size_t ws_size,
                              hipStream_t stream) {
    const float* x    = (const float*)d_in[0];
    const int*   ei   = (const int*)d_in[1];
    const int*   bat  = (const int*)d_in[2];
    const float* W1   = (const float*)d_in[3];
    const float* b1   = (const float*)d_in[4];
    const float* W2   = (const float*)d_in[5];
    const float* b2   = (const float*)d_in[6];
    const float* Wlin = (const float*)d_in[7];
    const float* blin = (const float*)d_in[8];

    const int N = in_sizes[2];      // 100000
    const int E = in_sizes[1] / 2;  // 3200000
    const int G = out_size / 2;     // 512
    const int* src  = ei;
    const int* dstv = ei + E;

    // ---- workspace layout ----
    int*   deg      = (int*)d_ws;             // N
    int*   cursor   = deg + N;                // N
    int*   blocksum = cursor + N;             // 256
    int*   csr_src  = blocksum + 256;         // E
    float* dinv     = (float*)(csr_src + E);  // N
    float* bufA     = dinv + N;               // N*64
    float* bufB     = bufA + (size_t)N * HF;  // N*64
    float* pool     = bufB + (size_t)N * HF;  // G*64
    float* cnt      = pool + (size_t)G * HF;  // G

    int nb = (N + 1023) / 1024;  // 98 <= 256

    // ---- CSR build (once, reused by both convs) ----
    hipMemsetAsync(deg, 0, (size_t)N * sizeof(int), stream);
    hist_kernel<<<(E + 255) / 256, 256, 0, stream>>>(dstv, deg, E);
    scan_partial<<<nb, 256, 0, stream>>>(deg, blocksum, N);
    scan_blocksums<<<1, 256, 0, stream>>>(blocksum, nb);
    scan_apply<<<nb, 256, 0, stream>>>(deg, blocksum, cursor, dinv, N);
    fill_kernel<<<(E + 255) / 256, 256, 0, stream>>>(src, dstv, cursor, csr_src, E);
    // now: cursor[d] = end offset, cursor[d]-deg[d] = begin offset

    // ---- conv1: bufA = (x@W1)*dinv ; bufB = relu(aggregate) ----
    gemm_scale_kernel<128><<<(N + 31) / 32, 256, 0, stream>>>(x, W1, dinv, bufA, N);
    agg_relu_kernel<<<(N + 3) / 4, 256, 0, stream>>>(bufA, cursor, deg, csr_src, dinv, b1,
                                                     bufB, N);

    // ---- conv2: bufA = (h1@W2)*dinv ; aggregate + relu + pool (h2 never materialized) ----
    gemm_scale_kernel<64><<<(N + 31) / 32, 256, 0, stream>>>(bufB, W2, dinv, bufA, N);
    hipMemsetAsync(pool, 0, ((size_t)G * HF + G) * sizeof(float), stream);
    agg_pool_kernel<<<(N + 3) / 4, 256, 0, stream>>>(bufA, cursor, deg, csr_src, dinv, b2,
                                                     bat, pool, cnt, N);

    final_kernel<<<G, HF, 0, stream>>>(pool, cnt, Wlin, blin, (float*)d_out);
}

// Round 15
// 976.484 us; speedup vs baseline: 2.0827x; 1.0068x over previous
//
#include <hip/hip_runtime.h>

#define HF 64  // hidden feature width (both convs output 64)
typedef unsigned short bfraw;  // bf16 as raw bits

__device__ __forceinline__ float bf2f(bfraw u) {
    return __uint_as_float((unsigned)u << 16);
}
__device__ __forceinline__ bfraw f2bf(float f) {
    unsigned u = __float_as_uint(f);
    unsigned r = (u + 0x7FFFu + ((u >> 16) & 1u)) >> 16;  // RNE
    return (bfraw)r;
}

// ---------------- CSR build: histogram ----------------
__global__ void hist_kernel(const int* __restrict__ dst, int* __restrict__ deg, int E) {
    int e = blockIdx.x * blockDim.x + threadIdx.x;
    if (e < E) atomicAdd(&deg[dst[e]], 1);
}

__global__ __launch_bounds__(256) void scan_partial(const int* __restrict__ deg,
                                                    int* __restrict__ blocksum, int N) {
    __shared__ int red[256];
    int base = blockIdx.x * 1024 + threadIdx.x * 4;
    int s = 0;
#pragma unroll
    for (int j = 0; j < 4; ++j) {
        int i = base + j;
        if (i < N) s += deg[i];
    }
    red[threadIdx.x] = s;
    __syncthreads();
    for (int o = 128; o > 0; o >>= 1) {
        if (threadIdx.x < o) red[threadIdx.x] += red[threadIdx.x + o];
        __syncthreads();
    }
    if (threadIdx.x == 0) blocksum[blockIdx.x] = red[0];
}

__global__ __launch_bounds__(256) void scan_blocksums(int* __restrict__ blocksum, int nb) {
    __shared__ int lds[256];
    int t = threadIdx.x;
    int v = (t < nb) ? blocksum[t] : 0;
    lds[t] = v;
    __syncthreads();
    for (int o = 1; o < 256; o <<= 1) {
        int add = (t >= o) ? lds[t - o] : 0;
        __syncthreads();
        lds[t] += add;
        __syncthreads();
    }
    if (t < nb) blocksum[t] = lds[t] - v;  // exclusive
}

__global__ __launch_bounds__(256) void scan_apply(const int* __restrict__ deg,
                                                  const int* __restrict__ blocksum,
                                                  int* __restrict__ cursor,
                                                  float* __restrict__ dinv, int N) {
    __shared__ int lds[256];
    int base = blockIdx.x * 1024 + threadIdx.x * 4;
    int v[4];
    int s = 0;
#pragma unroll
    for (int j = 0; j < 4; ++j) {
        int i = base + j;
        v[j] = (i < N) ? deg[i] : 0;
        s += v[j];
    }
    lds[threadIdx.x] = s;
    __syncthreads();
    for (int o = 1; o < 256; o <<= 1) {
        int add = (threadIdx.x >= o) ? lds[threadIdx.x - o] : 0;
        __syncthreads();
        lds[threadIdx.x] += add;
        __syncthreads();
    }
    int run = blocksum[blockIdx.x] + lds[threadIdx.x] - s;
#pragma unroll
    for (int j = 0; j < 4; ++j) {
        int i = base + j;
        if (i < N) {
            cursor[i] = run;
            dinv[i] = rsqrtf((float)v[j] + 1.0f);
            run += v[j];
        }
    }
}

__global__ void fill_kernel(const int* __restrict__ src, const int* __restrict__ dst,
                            int* __restrict__ cursor, int* __restrict__ csr_src, int E) {
    int e = blockIdx.x * blockDim.x + threadIdx.x;
    if (e < E) {
        int d = dst[e];
        int pos = atomicAdd(&cursor[d], 1);
        csr_src[pos] = src[e];
    }
}

// ---------------- conv1 GEMM: fp32 X -> bf16 Y = (X@W)*scale ----------------
template <int K>
__global__ __launch_bounds__(256) void gemm_scale_f32_kernel(const float* __restrict__ X,
                                                             const float* __restrict__ W,
                                                             const float* __restrict__ scale,
                                                             bfraw* __restrict__ Y, int N) {
    __shared__ float Wl[K * HF];
    __shared__ float xs[32 * K];
    for (int i = threadIdx.x; i < K * HF; i += 256) Wl[i] = W[i];

    int node0 = blockIdx.x * 32;
    const float4* X4 = (const float4*)(X + (size_t)node0 * K);
    float4* xs4 = (float4*)xs;
    int totalf4 = 32 * K / 4;
    for (int i = threadIdx.x; i < totalf4; i += 256) {
        int n = i / (K / 4);
        if (node0 + n < N) xs4[i] = X4[i];
    }
    __syncthreads();

    int wave = threadIdx.x >> 6, f = threadIdx.x & 63;
    for (int n = wave; n < 32; n += 4) {
        int node = node0 + n;
        if (node >= N) break;
        const float4* xr = (const float4*)&xs[n * K];
        float acc = 0.0f;
#pragma unroll
        for (int k4 = 0; k4 < K / 4; ++k4) {
            float4 xv = xr[k4];
            acc += xv.x * Wl[(k4 * 4 + 0) * HF + f];
            acc += xv.y * Wl[(k4 * 4 + 1) * HF + f];
            acc += xv.z * Wl[(k4 * 4 + 2) * HF + f];
            acc += xv.w * Wl[(k4 * 4 + 3) * HF + f];
        }
        Y[(size_t)node * HF + f] = f2bf(acc * scale[node]);
    }
}

// ---------------- conv2 GEMM: bf16 X -> bf16 Y = (X@W)*scale (K=64) --------------
__global__ __launch_bounds__(256) void gemm_scale_bf16_kernel(const bfraw* __restrict__ X,
                                                              const float* __restrict__ W,
                                                              const float* __restrict__ scale,
                                                              bfraw* __restrict__ Y, int N) {
    __shared__ float Wl[HF * HF];
    __shared__ float xs[32 * HF];
    for (int i = threadIdx.x; i < HF * HF; i += 256) Wl[i] = W[i];

    int node0 = blockIdx.x * 32;
    const ushort4* X4 = (const ushort4*)(X + (size_t)node0 * HF);
    for (int i = threadIdx.x; i < 32 * HF / 4; i += 256) {
        int n = i >> 4;  // 16 ushort4 per row
        if (node0 + n < N) {
            ushort4 u = X4[i];
            float4 fv = make_float4(bf2f(u.x), bf2f(u.y), bf2f(u.z), bf2f(u.w));
            ((float4*)xs)[i] = fv;
        }
    }
    __syncthreads();

    int wave = threadIdx.x >> 6, f = threadIdx.x & 63;
    for (int n = wave; n < 32; n += 4) {
        int node = node0 + n;
        if (node >= N) break;
        const float4* xr = (const float4*)&xs[n * HF];
        float acc = 0.0f;
#pragma unroll
        for (int k4 = 0; k4 < HF / 4; ++k4) {
            float4 xv = xr[k4];
            acc += xv.x * Wl[(k4 * 4 + 0) * HF + f];
            acc += xv.y * Wl[(k4 * 4 + 1) * HF + f];
            acc += xv.z * Wl[(k4 * 4 + 2) * HF + f];
            acc += xv.w * Wl[(k4 * 4 + 3) * HF + f];
        }
        Y[(size_t)node * HF + f] = f2bf(acc * scale[node]);
    }
}

// ---- wave-cooperative gather-sum (bf16 table): 32 independent gathers in flight ----
__device__ __forceinline__ float edge_gather_sum(const bfraw* __restrict__ hs,
                                                 const int* __restrict__ csr_src,
                                                 int beg, int end, int f) {
    float acc = 0.0f;
    for (int base = beg; base < end; base += 32) {
        int li = base + (f & 31);
        int myidx = csr_src[li < end ? li : beg];  // clamp: safe row, result masked
        int rem = end - base;                      // uniform
#pragma unroll
        for (int j = 0; j < 32; ++j) {
            int s = __builtin_amdgcn_readlane(myidx, j);
            float v = bf2f(hs[(size_t)s * HF + f]);
            acc += (j < rem) ? v : 0.0f;
        }
    }
    return acc;
}

// ---------------- conv1 aggregation + epilogue -> bf16 h1 ----------------
__global__ __launch_bounds__(256) void agg_relu_kernel(const bfraw* __restrict__ hs,
                                                       const int* __restrict__ cursor,
                                                       const int* __restrict__ deg,
                                                       const int* __restrict__ csr_src,
                                                       const float* __restrict__ dinv,
                                                       const float* __restrict__ b,
                                                       bfraw* __restrict__ out, int N) {
    int d = blockIdx.x * 4 + (threadIdx.x >> 6);
    if (d >= N) return;
    int f = threadIdx.x & 63;
    int end = cursor[d];
    int beg = end - deg[d];
    float acc = edge_gather_sum(hs, csr_src, beg, end, f);
    float self = bf2f(hs[(size_t)d * HF + f]);
    float v = dinv[d] * (acc + self) + b[f];
    out[(size_t)d * HF + f] = f2bf(fmaxf(v, 0.0f));
}

// ---------------- conv2 aggregation + relu + mean-pool accumulation ----------------
__global__ __launch_bounds__(256) void agg_pool_kernel(const bfraw* __restrict__ hs,
                                                       const int* __restrict__ cursor,
                                                       const int* __restrict__ deg,
                                                       const int* __restrict__ csr_src,
                                                       const float* __restrict__ dinv,
                                                       const float* __restrict__ b,
                                                       const int* __restrict__ batch,
                                                       float* __restrict__ pool,
                                                       float* __restrict__ cnt, int N) {
    int d = blockIdx.x * 4 + (threadIdx.x >> 6);
    if (d >= N) return;
    int f = threadIdx.x & 63;
    int end = cursor[d];
    int beg = end - deg[d];
    float acc = edge_gather_sum(hs, csr_src, beg, end, f);
    float self = bf2f(hs[(size_t)d * HF + f]);
    float v = fmaxf(dinv[d] * (acc + self) + b[f], 0.0f);
    int g = batch[d];
    atomicAdd(&pool[g * HF + f], v);
    if (f == 0) atomicAdd(&cnt[g], 1.0f);
}

// ---------------- final: out[g][c] = (pool[g]/cnt[g]) @ Wlin + blin ---------------------
__global__ void final_kernel(const float* __restrict__ pool, const float* __restrict__ cnt,
                             const float* __restrict__ Wlin, const float* __restrict__ blin,
                             float* __restrict__ out) {
    int g = blockIdx.x;
    int f = threadIdx.x;  // 64
    float v = pool[g * HF + f] / fmaxf(cnt[g], 1.0f);
    float s0 = v * Wlin[f * 2 + 0];
    float s1 = v * Wlin[f * 2 + 1];
#pragma unroll
    for (int off = 32; off > 0; off >>= 1) {
        s0 += __shfl_down(s0, off);
        s1 += __shfl_down(s1, off);
    }
    if (f == 0) {
        out[g * 2 + 0] = s0 + blin[0];
        out[g * 2 + 1] = s1 + blin[1];
    }
}

extern "C" void kernel_launch(void* const* d_in, const int* in_sizes, int n_in,
                              void* d_out, int out_size, void* d_ws, size_t ws_size,
                              hipStream_t stream) {
    const float* x    = (const float*)d_in[0];
    const int*   ei   = (const int*)d_in[1];
    const int*   bat  = (const int*)d_in[2];
    const float* W1   = (const float*)d_in[3];
    const float* b1   = (const float*)d_in[4];
    const float* W2   = (const float*)d_in[5];
    const float* b2   = (const float*)d_in[6];
    const float* Wlin = (const float*)d_in[7];
    const float* blin = (const float*)d_in[8];

    const int N = in_sizes[2];      // 100000
    const int E = in_sizes[1] / 2;  // 3200000
    const int G = out_size / 2;     // 512
    const int* src  = ei;
    const int* dstv = ei + E;

    // ---- workspace layout ----
    int*   deg      = (int*)d_ws;             // N
    int*   cursor   = deg + N;                // N
    int*   blocksum = cursor + N;             // 256
    int*   csr_src  = blocksum + 256;         // E
    float* dinv     = (float*)(csr_src + E);  // N
    float* pool     = dinv + N;               // G*64
    float* cnt      = pool + (size_t)G * HF;  // G
    uintptr_t p = (uintptr_t)(cnt + G);
    p = (p + 15) & ~(uintptr_t)15;
    bfraw* bufT = (bfraw*)p;                  // N*64 bf16 (msg table, reused conv1+conv2)
    bfraw* bufH = bufT + (size_t)N * HF;      // N*64 bf16 (h1)

    int nb = (N + 1023) / 1024;

    // ---- CSR build (once, reused by both convs) ----
    hipMemsetAsync(deg, 0, (size_t)N * sizeof(int), stream);
    hist_kernel<<<(E + 255) / 256, 256, 0, stream>>>(dstv, deg, E);
    scan_partial<<<nb, 256, 0, stream>>>(deg, blocksum, N);
    scan_blocksums<<<1, 256, 0, stream>>>(blocksum, nb);
    scan_apply<<<nb, 256, 0, stream>>>(deg, blocksum, cursor, dinv, N);
    fill_kernel<<<(E + 255) / 256, 256, 0, stream>>>(src, dstv, cursor, csr_src, E);

    // ---- conv1: bufT = bf16((x@W1)*dinv) ; bufH = bf16(relu(aggregate)) ----
    gemm_scale_f32_kernel<128><<<(N + 31) / 32, 256, 0, stream>>>(x, W1, dinv, bufT, N);
    agg_relu_kernel<<<(N + 3) / 4, 256, 0, stream>>>(bufT, cursor, deg, csr_src, dinv, b1,
                                                     bufH, N);

    // ---- conv2: bufT = bf16((h1@W2)*dinv) ; aggregate + relu + pool ----
    gemm_scale_bf16_kernel<<<(N + 31) / 32, 256, 0, stream>>>(bufH, W2, dinv, bufT, N);
    hipMemsetAsync(pool, 0, ((size_t)G * HF + G) * sizeof(float), stream);
    agg_pool_kernel<<<(N + 3) / 4, 256, 0, stream>>>(bufT, cursor, deg, csr_src, dinv, b2,
                                                     bat, pool, cnt, N);

    final_kernel<<<G, HF, 0, stream>>>(pool, cnt, Wlin, blin, (float*)d_out);
}

// Round 16
// 809.354 us; speedup vs baseline: 2.5128x; 1.2065x over previous
//
#include <hip/hip_runtime.h>

#define HF 64  // hidden feature width (both convs output 64)
typedef unsigned short bfraw;  // bf16 as raw bits

__device__ __forceinline__ float bf2f(bfraw u) {
    return __uint_as_float((unsigned)u << 16);
}
__device__ __forceinline__ bfraw f2bf(float f) {
    unsigned u = __float_as_uint(f);
    unsigned r = (u + 0x7FFFu + ((u >> 16) & 1u)) >> 16;  // RNE
    return (bfraw)r;
}

// ---------------- CSR build: histogram ----------------
__global__ void hist_kernel(const int* __restrict__ dst, int* __restrict__ deg, int E) {
    int e = blockIdx.x * blockDim.x + threadIdx.x;
    if (e < E) atomicAdd(&deg[dst[e]], 1);
}

__global__ __launch_bounds__(256) void scan_partial(const int* __restrict__ deg,
                                                    int* __restrict__ blocksum, int N) {
    __shared__ int red[256];
    int base = blockIdx.x * 1024 + threadIdx.x * 4;
    int s = 0;
#pragma unroll
    for (int j = 0; j < 4; ++j) {
        int i = base + j;
        if (i < N) s += deg[i];
    }
    red[threadIdx.x] = s;
    __syncthreads();
    for (int o = 128; o > 0; o >>= 1) {
        if (threadIdx.x < o) red[threadIdx.x] += red[threadIdx.x + o];
        __syncthreads();
    }
    if (threadIdx.x == 0) blocksum[blockIdx.x] = red[0];
}

__global__ __launch_bounds__(256) void scan_blocksums(int* __restrict__ blocksum, int nb) {
    __shared__ int lds[256];
    int t = threadIdx.x;
    int v = (t < nb) ? blocksum[t] : 0;
    lds[t] = v;
    __syncthreads();
    for (int o = 1; o < 256; o <<= 1) {
        int add = (t >= o) ? lds[t - o] : 0;
        __syncthreads();
        lds[t] += add;
        __syncthreads();
    }
    if (t < nb) blocksum[t] = lds[t] - v;  // exclusive
}

__global__ __launch_bounds__(256) void scan_apply(const int* __restrict__ deg,
                                                  const int* __restrict__ blocksum,
                                                  int* __restrict__ cursor,
                                                  float* __restrict__ dinv, int N) {
    __shared__ int lds[256];
    int base = blockIdx.x * 1024 + threadIdx.x * 4;
    int v[4];
    int s = 0;
#pragma unroll
    for (int j = 0; j < 4; ++j) {
        int i = base + j;
        v[j] = (i < N) ? deg[i] : 0;
        s += v[j];
    }
    lds[threadIdx.x] = s;
    __syncthreads();
    for (int o = 1; o < 256; o <<= 1) {
        int add = (threadIdx.x >= o) ? lds[threadIdx.x - o] : 0;
        __syncthreads();
        lds[threadIdx.x] += add;
        __syncthreads();
    }
    int run = blocksum[blockIdx.x] + lds[threadIdx.x] - s;
#pragma unroll
    for (int j = 0; j < 4; ++j) {
        int i = base + j;
        if (i < N) {
            cursor[i] = run;
            dinv[i] = rsqrtf((float)v[j] + 1.0f);
            run += v[j];
        }
    }
}

// XCD-partitioned fill: partition p (= blockIdx%8, matches round-robin XCD dispatch)
// handles dst range [p*part, (p+1)*part). Each csr_src line is written from ONE XCD
// -> stays in that XCD's L2, written back once (kills the 16x write amplification).
__global__ __launch_bounds__(256) void fill_kernel(const int* __restrict__ src,
                                                   const int* __restrict__ dst,
                                                   int* __restrict__ cursor,
                                                   int* __restrict__ csr_src,
                                                   int E, int part, int nblk) {
    int p = blockIdx.x & 7;
    int blk = blockIdx.x >> 3;
    int plo = p * part;
    int phi = plo + part;
    for (int e = blk * 256 + threadIdx.x; e < E; e += nblk * 256) {
        int d = dst[e];
        if (d >= plo && d < phi) {
            int pos = atomicAdd(&cursor[d], 1);
            csr_src[pos] = src[e];
        }
    }
}

// ---------------- conv1 GEMM: fp32 X -> bf16 Y = (X@W)*scale ----------------
template <int K>
__global__ __launch_bounds__(256) void gemm_scale_f32_kernel(const float* __restrict__ X,
                                                             const float* __restrict__ W,
                                                             const float* __restrict__ scale,
                                                             bfraw* __restrict__ Y, int N) {
    __shared__ float Wl[K * HF];
    __shared__ float xs[32 * K];
    for (int i = threadIdx.x; i < K * HF; i += 256) Wl[i] = W[i];

    int node0 = blockIdx.x * 32;
    const float4* X4 = (const float4*)(X + (size_t)node0 * K);
    float4* xs4 = (float4*)xs;
    int totalf4 = 32 * K / 4;
    for (int i = threadIdx.x; i < totalf4; i += 256) {
        int n = i / (K / 4);
        if (node0 + n < N) xs4[i] = X4[i];
    }
    __syncthreads();

    int wave = threadIdx.x >> 6, f = threadIdx.x & 63;
    for (int n = wave; n < 32; n += 4) {
        int node = node0 + n;
        if (node >= N) break;
        const float4* xr = (const float4*)&xs[n * K];
        float acc = 0.0f;
#pragma unroll
        for (int k4 = 0; k4 < K / 4; ++k4) {
            float4 xv = xr[k4];
            acc += xv.x * Wl[(k4 * 4 + 0) * HF + f];
            acc += xv.y * Wl[(k4 * 4 + 1) * HF + f];
            acc += xv.z * Wl[(k4 * 4 + 2) * HF + f];
            acc += xv.w * Wl[(k4 * 4 + 3) * HF + f];
        }
        Y[(size_t)node * HF + f] = f2bf(acc * scale[node]);
    }
}

// ---------------- conv2 GEMM: bf16 X -> bf16 Y = (X@W)*scale (K=64) --------------
__global__ __launch_bounds__(256) void gemm_scale_bf16_kernel(const bfraw* __restrict__ X,
                                                              const float* __restrict__ W,
                                                              const float* __restrict__ scale,
                                                              bfraw* __restrict__ Y, int N) {
    __shared__ float Wl[HF * HF];
    __shared__ float xs[32 * HF];
    for (int i = threadIdx.x; i < HF * HF; i += 256) Wl[i] = W[i];

    int node0 = blockIdx.x * 32;
    const ushort4* X4 = (const ushort4*)(X + (size_t)node0 * HF);
    for (int i = threadIdx.x; i < 32 * HF / 4; i += 256) {
        int n = i >> 4;  // 16 ushort4 per row
        if (node0 + n < N) {
            ushort4 u = X4[i];
            float4 fv = make_float4(bf2f(u.x), bf2f(u.y), bf2f(u.z), bf2f(u.w));
            ((float4*)xs)[i] = fv;
        }
    }
    __syncthreads();

    int wave = threadIdx.x >> 6, f = threadIdx.x & 63;
    for (int n = wave; n < 32; n += 4) {
        int node = node0 + n;
        if (node >= N) break;
        const float4* xr = (const float4*)&xs[n * HF];
        float acc = 0.0f;
#pragma unroll
        for (int k4 = 0; k4 < HF / 4; ++k4) {
            float4 xv = xr[k4];
            acc += xv.x * Wl[(k4 * 4 + 0) * HF + f];
            acc += xv.y * Wl[(k4 * 4 + 1) * HF + f];
            acc += xv.z * Wl[(k4 * 4 + 2) * HF + f];
            acc += xv.w * Wl[(k4 * 4 + 3) * HF + f];
        }
        Y[(size_t)node * HF + f] = f2bf(acc * scale[node]);
    }
}

// ---- wave-cooperative gather-sum with EXPLICIT register staging (v[32]) ----
// All 32 gathers issued into distinct VGPRs before any consume -> true MLP.
// (Round-15 profile: VGPR=36 proved the compiler batched loads; this forces depth 32.)
__device__ __forceinline__ float edge_gather_sum(const bfraw* __restrict__ hs,
                                                 const int* __restrict__ csr_src,
                                                 int beg, int end, int f) {
    float acc = 0.0f;
    int base = beg;
    // full chunks: no clamp, no per-edge select
    for (; base + 32 <= end; base += 32) {
        int myidx = csr_src[base + (f & 31)];
        float v[32];
#pragma unroll
        for (int j = 0; j < 32; ++j) {
            int s = __builtin_amdgcn_readlane(myidx, j);
            v[j] = bf2f(hs[(size_t)s * HF + f]);
        }
#pragma unroll
        for (int j = 0; j < 32; ++j) acc += v[j];
    }
    if (base < end) {
        int li = base + (f & 31);
        int myidx = csr_src[li < end ? li : base];  // clamp: safe, masked below
        int rem = end - base;                       // uniform
        float v[32];
#pragma unroll
        for (int j = 0; j < 32; ++j) {
            int s = __builtin_amdgcn_readlane(myidx, j);
            v[j] = bf2f(hs[(size_t)s * HF + f]);
        }
#pragma unroll
        for (int j = 0; j < 32; ++j) acc += (j < rem) ? v[j] : 0.0f;
    }
    return acc;
}

// ---------------- conv1 aggregation + epilogue -> bf16 h1 ----------------
__global__ __launch_bounds__(256) void agg_relu_kernel(const bfraw* __restrict__ hs,
                                                       const int* __restrict__ cursor,
                                                       const int* __restrict__ deg,
                                                       const int* __restrict__ csr_src,
                                                       const float* __restrict__ dinv,
                                                       const float* __restrict__ b,
                                                       bfraw* __restrict__ out, int N) {
    int d = blockIdx.x * 4 + (threadIdx.x >> 6);
    if (d >= N) return;
    int f = threadIdx.x & 63;
    int end = cursor[d];
    int beg = end - deg[d];
    float acc = edge_gather_sum(hs, csr_src, beg, end, f);
    float self = bf2f(hs[(size_t)d * HF + f]);
    float v = dinv[d] * (acc + self) + b[f];
    out[(size_t)d * HF + f] = f2bf(fmaxf(v, 0.0f));
}

// ---------------- conv2 aggregation + relu + mean-pool accumulation ----------------
__global__ __launch_bounds__(256) void agg_pool_kernel(const bfraw* __restrict__ hs,
                                                       const int* __restrict__ cursor,
                                                       const int* __restrict__ deg,
                                                       const int* __restrict__ csr_src,
                                                       const float* __restrict__ dinv,
                                                       const float* __restrict__ b,
                                                       const int* __restrict__ batch,
                                                       float* __restrict__ pool,
                                                       float* __restrict__ cnt, int N) {
    int d = blockIdx.x * 4 + (threadIdx.x >> 6);
    if (d >= N) return;
    int f = threadIdx.x & 63;
    int end = cursor[d];
    int beg = end - deg[d];
    float acc = edge_gather_sum(hs, csr_src, beg, end, f);
    float self = bf2f(hs[(size_t)d * HF + f]);
    float v = fmaxf(dinv[d] * (acc + self) + b[f], 0.0f);
    int g = batch[d];
    atomicAdd(&pool[g * HF + f], v);
    if (f == 0) atomicAdd(&cnt[g], 1.0f);
}

// ---------------- final: out[g][c] = (pool[g]/cnt[g]) @ Wlin + blin ---------------------
__global__ void final_kernel(const float* __restrict__ pool, const float* __restrict__ cnt,
                             const float* __restrict__ Wlin, const float* __restrict__ blin,
                             float* __restrict__ out) {
    int g = blockIdx.x;
    int f = threadIdx.x;  // 64
    float v = pool[g * HF + f] / fmaxf(cnt[g], 1.0f);
    float s0 = v * Wlin[f * 2 + 0];
    float s1 = v * Wlin[f * 2 + 1];
#pragma unroll
    for (int off = 32; off > 0; off >>= 1) {
        s0 += __shfl_down(s0, off);
        s1 += __shfl_down(s1, off);
    }
    if (f == 0) {
        out[g * 2 + 0] = s0 + blin[0];
        out[g * 2 + 1] = s1 + blin[1];
    }
}

extern "C" void kernel_launch(void* const* d_in, const int* in_sizes, int n_in,
                              void* d_out, int out_size, void* d_ws, size_t ws_size,
                              hipStream_t stream) {
    const float* x    = (const float*)d_in[0];
    const int*   ei   = (const int*)d_in[1];
    const int*   bat  = (const int*)d_in[2];
    const float* W1   = (const float*)d_in[3];
    const float* b1   = (const float*)d_in[4];
    const float* W2   = (const float*)d_in[5];
    const float* b2   = (const float*)d_in[6];
    const float* Wlin = (const float*)d_in[7];
    const float* blin = (const float*)d_in[8];

    const int N = in_sizes[2];      // 100000
    const int E = in_sizes[1] / 2;  // 3200000
    const int G = out_size / 2;     // 512
    const int* src  = ei;
    const int* dstv = ei + E;

    // ---- workspace layout ----
    int*   deg      = (int*)d_ws;             // N
    int*   cursor   = deg + N;                // N
    int*   blocksum = cursor + N;             // 256
    int*   csr_src  = blocksum + 256;         // E
    float* dinv     = (float*)(csr_src + E);  // N
    float* pool     = dinv + N;               // G*64
    float* cnt      = pool + (size_t)G * HF;  // G
    uintptr_t p = (uintptr_t)(cnt + G);
    p = (p + 15) & ~(uintptr_t)15;
    bfraw* bufT = (bfraw*)p;                  // N*64 bf16 (msg table, reused conv1+conv2)
    bfraw* bufH = bufT + (size_t)N * HF;      // N*64 bf16 (h1)

    int nb = (N + 1023) / 1024;

    // ---- CSR build (once, reused by both convs) ----
    hipMemsetAsync(deg, 0, (size_t)N * sizeof(int), stream);
    hist_kernel<<<(E + 255) / 256, 256, 0, stream>>>(dstv, deg, E);
    scan_partial<<<nb, 256, 0, stream>>>(deg, blocksum, N);
    scan_blocksums<<<1, 256, 0, stream>>>(blocksum, nb);
    scan_apply<<<nb, 256, 0, stream>>>(deg, blocksum, cursor, dinv, N);
    const int part = (N + 7) / 8;
    const int nblk = 512;  // blocks per partition; grid = 8*nblk
    fill_kernel<<<8 * nblk, 256, 0, stream>>>(src, dstv, cursor, csr_src, E, part, nblk);

    // ---- conv1: bufT = bf16((x@W1)*dinv) ; bufH = bf16(relu(aggregate)) ----
    gemm_scale_f32_kernel<128><<<(N + 31) / 32, 256, 0, stream>>>(x, W1, dinv, bufT, N);
    agg_relu_kernel<<<(N + 3) / 4, 256, 0, stream>>>(bufT, cursor, deg, csr_src, dinv, b1,
                                                     bufH, N);

    // ---- conv2: bufT = bf16((h1@W2)*dinv) ; aggregate + relu + pool ----
    gemm_scale_bf16_kernel<<<(N + 31) / 32, 256, 0, stream>>>(bufH, W2, dinv, bufT, N);
    hipMemsetAsync(pool, 0, ((size_t)G * HF + G) * sizeof(float), stream);
    agg_pool_kernel<<<(N + 3) / 4, 256, 0, stream>>>(bufT, cursor, deg, csr_src, dinv, b2,
                                                     bat, pool, cnt, N);

    final_kernel<<<G, HF, 0, stream>>>(pool, cnt, Wlin, blin, (float*)d_out);
}